// Round 1
// baseline (635.213 us; speedup 1.0000x reference)
//
#include <hip/hip_runtime.h>

// ---------------------------------------------------------------------------
// Fused TransformerBlock: x += MSA(LN(x)) twice, then x += MLP(LN(x)).
// B=4 T=1024 C=1024 H=16 hd=64. All activations fp32 at residual level,
// bf16 at GEMM inputs (MFMA 16x16x32_bf16), softmax/LN/reductions fp32.
// ---------------------------------------------------------------------------

#define DEVI __device__ __forceinline__

typedef unsigned short u16;
typedef short bf16x8 __attribute__((ext_vector_type(8)));   // 8 bf16 = 4 VGPR
typedef float f32x4 __attribute__((ext_vector_type(4)));
typedef unsigned short u16x4 __attribute__((ext_vector_type(4)));

DEVI u16 f2bf(float f) {                 // RNE fp32 -> bf16
  union { float f; unsigned u; } v; v.f = f;
  unsigned r = v.u + 0x7FFFu + ((v.u >> 16) & 1u);
  return (u16)(r >> 16);
}

DEVI void gload16(const void* g, void* l) {   // async global->LDS, 16B/lane
  __builtin_amdgcn_global_load_lds((const __attribute__((address_space(1))) void*)g,
                                   (__attribute__((address_space(3))) void*)l,
                                   16, 0, 0);
}

// ---------------------------------------------------------------------------
// Weight packs (fp32 -> bf16, transposed to Bt[N][K] layout for the GEMM)
// ---------------------------------------------------------------------------

// W [16][1024][64] fp32  ->  out rows [h*64+d][1024] bf16
__global__ __launch_bounds__(256) void k_pack_headw(const float* __restrict__ W,
                                                    u16* __restrict__ out) {
  const int k0 = blockIdx.x * 64;
  const int h  = blockIdx.y;
  __shared__ float t[64][65];
  const int tid = threadIdx.x;
#pragma unroll
  for (int p = 0; p < 16; p++) {
    int e = p * 256 + tid, kk = e >> 6, d = e & 63;
    t[kk][d] = W[h * 65536 + (k0 + kk) * 64 + d];
  }
  __syncthreads();
#pragma unroll
  for (int p = 0; p < 16; p++) {
    int e = p * 256 + tid, d = e >> 6, kk = e & 63;
    out[(size_t)(h * 64 + d) * 1024 + k0 + kk] = f2bf(t[kk][d]);
  }
}

// in [R][C] fp32 -> out [C][R] bf16
__global__ __launch_bounds__(256) void k_transpose(const float* __restrict__ in,
                                                   u16* __restrict__ out,
                                                   int R, int C) {
  const int c0 = blockIdx.x * 64, r0 = blockIdx.y * 64;
  __shared__ float t[64][65];
  const int tid = threadIdx.x;
#pragma unroll
  for (int p = 0; p < 16; p++) {
    int e = p * 256 + tid, rr = e >> 6, cc = e & 63;
    t[rr][cc] = in[(size_t)(r0 + rr) * C + c0 + cc];
  }
  __syncthreads();
#pragma unroll
  for (int p = 0; p < 16; p++) {
    int e = p * 256 + tid, cc = e >> 6, rr = e & 63;
    out[(size_t)(c0 + cc) * R + r0 + rr] = f2bf(t[rr][cc]);
  }
}

// ---------------------------------------------------------------------------
// LayerNorm (optionally fused residual add): xv = xin (+ oin); writes fp32
// running residual (xsum) and bf16 normalized output (xn). One block per row.
// ---------------------------------------------------------------------------
__global__ __launch_bounds__(256) void k_ln(const float* __restrict__ xin,
                                            const float* __restrict__ oin,
                                            float* __restrict__ xsum,
                                            u16* __restrict__ xn,
                                            const float* __restrict__ g,
                                            const float* __restrict__ b) {
  const int row = blockIdx.x;
  const size_t base = (size_t)row * 1024;
  const int tid = threadIdx.x;
  float4 xv = ((const float4*)(xin + base))[tid];
  if (oin) {
    float4 ov = ((const float4*)(oin + base))[tid];
    xv.x += ov.x; xv.y += ov.y; xv.z += ov.z; xv.w += ov.w;
  }
  if (xsum) ((float4*)(xsum + base))[tid] = xv;
  float s = xv.x + xv.y + xv.z + xv.w;
  float q = xv.x * xv.x + xv.y * xv.y + xv.z * xv.z + xv.w * xv.w;
#pragma unroll
  for (int m = 1; m < 64; m <<= 1) { s += __shfl_xor(s, m); q += __shfl_xor(q, m); }
  __shared__ float red[8];
  const int wave = tid >> 6, lane = tid & 63;
  if (lane == 0) { red[wave] = s; red[4 + wave] = q; }
  __syncthreads();
  s = red[0] + red[1] + red[2] + red[3];
  q = red[4] + red[5] + red[6] + red[7];
  const float mean = s * (1.f / 1024.f);
  const float var  = q * (1.f / 1024.f) - mean * mean;
  const float rstd = rsqrtf(var + 1e-5f);
  float4 gv = ((const float4*)g)[tid];
  float4 bv = ((const float4*)b)[tid];
  u16x4 o;
  o[0] = f2bf((xv.x - mean) * rstd * gv.x + bv.x);
  o[1] = f2bf((xv.y - mean) * rstd * gv.y + bv.y);
  o[2] = f2bf((xv.z - mean) * rstd * gv.z + bv.z);
  o[3] = f2bf((xv.w - mean) * rstd * gv.w + bv.w);
  *(u16x4*)(xn + base + tid * 4) = o;
}

// ---------------------------------------------------------------------------
// GEMM C[M,N] = A[M,K] * Bt[N,K]^T, bf16 in, fp32 accum. m97 structure:
// 128x128 tile, BK=32, 4 waves (2x2) x 64x64, global_load_lds width-16.
// EPI 0: bf16 store. 1: +bias, relu, bf16. 2: +bias +resid, fp32 store.
// ---------------------------------------------------------------------------
template <int EPI>
__global__ __launch_bounds__(256) void gemm_bt(const u16* __restrict__ A,
                                               const u16* __restrict__ Bt,
                                               void* __restrict__ outp,
                                               const float* __restrict__ bias,
                                               const float* __restrict__ resid,
                                               int M, int N, int K) {
  __shared__ u16 As[128 * 32];
  __shared__ u16 Bs[128 * 32];
  const int tid = threadIdx.x;
  const int wave = tid >> 6, lane = tid & 63;
  const int lg = lane >> 4, l15 = lane & 15;
  const int wr = wave >> 1, wc = wave & 1;
  const int by = blockIdx.y, bx = blockIdx.x;

  const u16* Ab = A + (size_t)by * 128 * K;
  const u16* Bb = Bt + (size_t)bx * 128 * K;

  // staging: 512 chunks of 16B per 8KB tile; thread covers chunk tid and 256+tid
  const int r0 = tid >> 2, c0 = (tid & 3) * 8;
  const int r1 = (256 + tid) >> 2;
  char* lA0 = (char*)As + (wave * 64) * 16;          // wave-uniform LDS dst
  char* lA1 = (char*)As + (256 + wave * 64) * 16;
  char* lB0 = (char*)Bs + (wave * 64) * 16;
  char* lB1 = (char*)Bs + (256 + wave * 64) * 16;

  const f32x4 zero = {0.f, 0.f, 0.f, 0.f};
  f32x4 acc[4][4];
#pragma unroll
  for (int i = 0; i < 4; i++)
#pragma unroll
    for (int j = 0; j < 4; j++) acc[i][j] = zero;

  for (int kk = 0; kk < K; kk += 32) {
    gload16(Ab + (size_t)r0 * K + kk + c0, lA0);
    gload16(Ab + (size_t)r1 * K + kk + c0, lA1);
    gload16(Bb + (size_t)r0 * K + kk + c0, lB0);
    gload16(Bb + (size_t)r1 * K + kk + c0, lB1);
    __syncthreads();   // vmcnt(0) drain + barrier: tiles resident
    bf16x8 af[4], bfv[4];
#pragma unroll
    for (int i = 0; i < 4; i++)
      af[i] = *(const bf16x8*)&As[(wr * 64 + i * 16 + l15) * 32 + lg * 8];
#pragma unroll
    for (int j = 0; j < 4; j++)
      bfv[j] = *(const bf16x8*)&Bs[(wc * 64 + j * 16 + l15) * 32 + lg * 8];
#pragma unroll
    for (int i = 0; i < 4; i++)
#pragma unroll
      for (int j = 0; j < 4; j++)
        acc[i][j] = __builtin_amdgcn_mfma_f32_16x16x32_bf16(af[i], bfv[j], acc[i][j], 0, 0, 0);
    __syncthreads();   // all waves done reading before next stage overwrites
  }

  // C/D layout: col = lane&15, row = (lane>>4)*4 + reg  [m89/m91 verified]
  const int rbase = by * 128 + wr * 64 + lg * 4;
  const int cbase = bx * 128 + wc * 64 + l15;
  if constexpr (EPI == 0) {
    u16* out = (u16*)outp;
#pragma unroll
    for (int i = 0; i < 4; i++)
#pragma unroll
      for (int j = 0; j < 4; j++)
#pragma unroll
        for (int r = 0; r < 4; r++)
          out[(size_t)(rbase + i * 16 + r) * N + cbase + j * 16] = f2bf(acc[i][j][r]);
  } else if constexpr (EPI == 1) {
    u16* out = (u16*)outp;
#pragma unroll
    for (int j = 0; j < 4; j++) {
      const float bv = bias[cbase + j * 16];
#pragma unroll
      for (int i = 0; i < 4; i++)
#pragma unroll
        for (int r = 0; r < 4; r++)
          out[(size_t)(rbase + i * 16 + r) * N + cbase + j * 16] =
              f2bf(fmaxf(acc[i][j][r] + bv, 0.f));
    }
  } else {
    float* out = (float*)outp;
#pragma unroll
    for (int j = 0; j < 4; j++) {
      const float bv = bias[cbase + j * 16];
#pragma unroll
      for (int i = 0; i < 4; i++)
#pragma unroll
        for (int r = 0; r < 4; r++) {
          const size_t idx = (size_t)(rbase + i * 16 + r) * N + cbase + j * 16;
          out[idx] = acc[i][j][r] + bv + resid[idx];
        }
    }
  }
}

// ---------------------------------------------------------------------------
// V transpose: QKV[.,2048+h*64+d] -> Vt[b][h][d][t]  (bf16)
// ---------------------------------------------------------------------------
__global__ __launch_bounds__(256) void k_vt(const u16* __restrict__ QKV,
                                            u16* __restrict__ Vt) {
  const int bh = blockIdx.y, b = bh >> 4, h = bh & 15;
  const int t0 = blockIdx.x * 64;
  __shared__ u16 tile[64][66];
  const int tid = threadIdx.x;
#pragma unroll
  for (int p = 0; p < 16; p++) {
    int e = p * 256 + tid, tt = e >> 6, d = e & 63;
    tile[tt][d] = QKV[(size_t)(b * 1024 + t0 + tt) * 3072 + 2048 + h * 64 + d];
  }
  __syncthreads();
#pragma unroll
  for (int p = 0; p < 16; p++) {
    int e = p * 256 + tid, d = e >> 6, tt = e & 63;
    Vt[((size_t)bh * 64 + d) * 1024 + t0 + tt] = tile[tt][d];
  }
}

// ---------------------------------------------------------------------------
// Flash attention fwd. Block = (b,h) x 64 q-rows, 4 waves x 16 rows each.
// KV tiles of 32. K straight from QKV (contiguous in d); V via Vt (contig t).
// S scale = C^-0.5 = 1/32 (reference scales by EMBED, not head dim!).
// Online softmax in fp32, wave-parallel via shfl_xor over 16-lane groups.
// ---------------------------------------------------------------------------
__global__ __launch_bounds__(256) void k_attn(const u16* __restrict__ QKV,
                                              const u16* __restrict__ Vt,
                                              float* __restrict__ O) {
  const int Tn = 1024;
  const int bh = blockIdx.x, b = bh >> 4, h = bh & 15;
  const int q0 = blockIdx.y * 64;
  const int tid = threadIdx.x, wave = tid >> 6, lane = tid & 63;
  const int lg = lane >> 4, l15 = lane & 15;

  const u16* Qb = QKV + (size_t)(b * Tn + q0 + wave * 16 + l15) * 3072 + h * 64 + lg * 8;
  const bf16x8 aq0 = *(const bf16x8*)Qb;
  const bf16x8 aq1 = *(const bf16x8*)(Qb + 32);
  const u16* Kb = QKV + (size_t)(b * Tn) * 3072 + 1024 + h * 64;
  const u16* Vb = Vt + (size_t)bh * 64 * Tn;

  __shared__ u16 P[4][16][56];   // per-wave P tile, stride 56 u16 (16B aligned rows)

  float m[4] = {-1e30f, -1e30f, -1e30f, -1e30f};
  float sden[4] = {0.f, 0.f, 0.f, 0.f};
  const f32x4 zero = {0.f, 0.f, 0.f, 0.f};
  f32x4 oa[4] = {zero, zero, zero, zero};

  for (int kv = 0; kv < Tn; kv += 32) {
    f32x4 sa0 = zero, sa1 = zero;
    const u16* kp0 = Kb + (size_t)(kv + l15) * 3072 + lg * 8;
    const u16* kp1 = Kb + (size_t)(kv + 16 + l15) * 3072 + lg * 8;
    sa0 = __builtin_amdgcn_mfma_f32_16x16x32_bf16(aq0, *(const bf16x8*)kp0, sa0, 0, 0, 0);
    sa0 = __builtin_amdgcn_mfma_f32_16x16x32_bf16(aq1, *(const bf16x8*)(kp0 + 32), sa0, 0, 0, 0);
    sa1 = __builtin_amdgcn_mfma_f32_16x16x32_bf16(aq0, *(const bf16x8*)kp1, sa1, 0, 0, 0);
    sa1 = __builtin_amdgcn_mfma_f32_16x16x32_bf16(aq1, *(const bf16x8*)(kp1 + 32), sa1, 0, 0, 0);
    sa0 *= 0.03125f; sa1 *= 0.03125f;

    float fr[4];
#pragma unroll
    for (int r = 0; r < 4; r++) {
      float v = fmaxf(sa0[r], sa1[r]);
      v = fmaxf(v, __shfl_xor(v, 1));
      v = fmaxf(v, __shfl_xor(v, 2));
      v = fmaxf(v, __shfl_xor(v, 4));
      v = fmaxf(v, __shfl_xor(v, 8));
      const float mn = fmaxf(m[r], v);
      fr[r] = __expf(m[r] - mn);
      m[r] = mn;
      const float p0 = __expf(sa0[r] - mn);
      const float p1 = __expf(sa1[r] - mn);
      P[wave][lg * 4 + r][l15] = f2bf(p0);
      P[wave][lg * 4 + r][16 + l15] = f2bf(p1);
      float ts = p0 + p1;
      ts += __shfl_xor(ts, 1);
      ts += __shfl_xor(ts, 2);
      ts += __shfl_xor(ts, 4);
      ts += __shfl_xor(ts, 8);
      sden[r] = sden[r] * fr[r] + ts;
    }
#pragma unroll
    for (int dg = 0; dg < 4; dg++) {
      oa[dg][0] *= fr[0]; oa[dg][1] *= fr[1];
      oa[dg][2] *= fr[2]; oa[dg][3] *= fr[3];
    }
    const bf16x8 ap = *(const bf16x8*)&P[wave][l15][lg * 8];
#pragma unroll
    for (int dg = 0; dg < 4; dg++) {
      const u16* vp = Vb + (size_t)(dg * 16 + l15) * Tn + kv + lg * 8;
      oa[dg] = __builtin_amdgcn_mfma_f32_16x16x32_bf16(ap, *(const bf16x8*)vp, oa[dg], 0, 0, 0);
    }
  }

  float* Ob = O + (size_t)(b * Tn + q0 + wave * 16) * 1024 + h * 64;
#pragma unroll
  for (int dg = 0; dg < 4; dg++)
#pragma unroll
    for (int r = 0; r < 4; r++)
      Ob[(size_t)(lg * 4 + r) * 1024 + dg * 16 + l15] = oa[dg][r] / sden[r];
}

// ---------------------------------------------------------------------------
// Launch
// ---------------------------------------------------------------------------
extern "C" void kernel_launch(void* const* d_in, const int* in_sizes, int n_in,
                              void* d_out, int out_size, void* d_ws, size_t ws_size,
                              hipStream_t stream) {
  const float* x   = (const float*)d_in[0];
  const float* Wq1 = (const float*)d_in[1];
  const float* Wk1 = (const float*)d_in[2];
  const float* Wv1 = (const float*)d_in[3];
  const float* Wq2 = (const float*)d_in[4];
  const float* Wk2 = (const float*)d_in[5];
  const float* Wv2 = (const float*)d_in[6];
  const float* g1  = (const float*)d_in[7];
  const float* b1  = (const float*)d_in[8];
  const float* g2  = (const float*)d_in[9];
  const float* b2  = (const float*)d_in[10];
  const float* g3  = (const float*)d_in[11];
  const float* b3  = (const float*)d_in[12];
  const float* W1  = (const float*)d_in[13];
  const float* bf1 = (const float*)d_in[14];
  const float* W2  = (const float*)d_in[15];
  const float* bf2 = (const float*)d_in[16];

  char* ws = (char*)d_ws;
  // layout (bytes):
  u16* Wqkv1t = (u16*)(ws);                    //  6,291,456  [3072][1024]
  u16* Wqkv2t = (u16*)(ws + 6291456);          //  6,291,456
  u16* W1t    = (u16*)(ws + 12582912);         //  8,388,608  [4096][1024]
  u16* W2t    = (u16*)(ws + 20971520);         //  8,388,608  [1024][4096]
  u16* xn     = (u16*)(ws + 29360128);         //  8,388,608  [4096][1024]
  u16* QKV    = (u16*)(ws + 37748736);         // 25,165,824  [4096][3072]
  u16* Vt     = (u16*)(ws + 62914560);         //  8,388,608  [64][64][1024]
  float* O    = (float*)(ws + 71303168);       // 16,777,216  [4096][1024]
  u16* h1     = (u16*)(ws + 37748736);         // 33,554,432  aliases QKV+Vt (dead by MLP)
  float* xacc = (float*)d_out;                 // fp32 running residual lives in d_out
  // total ws = 88,080,384 bytes

  const dim3 blk(256);

  // weight packs
  k_pack_headw<<<dim3(16, 16), blk, 0, stream>>>(Wq1, Wqkv1t);
  k_pack_headw<<<dim3(16, 16), blk, 0, stream>>>(Wk1, Wqkv1t + 1024 * 1024);
  k_pack_headw<<<dim3(16, 16), blk, 0, stream>>>(Wv1, Wqkv1t + 2048 * 1024);
  k_pack_headw<<<dim3(16, 16), blk, 0, stream>>>(Wq2, Wqkv2t);
  k_pack_headw<<<dim3(16, 16), blk, 0, stream>>>(Wk2, Wqkv2t + 1024 * 1024);
  k_pack_headw<<<dim3(16, 16), blk, 0, stream>>>(Wv2, Wqkv2t + 2048 * 1024);
  k_transpose<<<dim3(64, 16), blk, 0, stream>>>(W1, W1t, 1024, 4096);
  k_transpose<<<dim3(16, 64), blk, 0, stream>>>(W2, W2t, 4096, 1024);

  // ---- layer 1 MSA ----
  k_ln<<<4096, blk, 0, stream>>>(x, nullptr, nullptr, xn, g1, b1);
  gemm_bt<0><<<dim3(24, 32), blk, 0, stream>>>(xn, Wqkv1t, QKV, nullptr, nullptr, 4096, 3072, 1024);
  k_vt<<<dim3(16, 64), blk, 0, stream>>>(QKV, Vt);
  k_attn<<<dim3(64, 16), blk, 0, stream>>>(QKV, Vt, O);
  // x2 = x + O; xn = LN(x2)
  k_ln<<<4096, blk, 0, stream>>>(x, O, xacc, xn, g2, b2);

  // ---- layer 2 MSA ----
  gemm_bt<0><<<dim3(24, 32), blk, 0, stream>>>(xn, Wqkv2t, QKV, nullptr, nullptr, 4096, 3072, 1024);
  k_vt<<<dim3(16, 64), blk, 0, stream>>>(QKV, Vt);
  k_attn<<<dim3(64, 16), blk, 0, stream>>>(QKV, Vt, O);
  // x3 = x2 + O (in place in d_out); xn = LN(x3)
  k_ln<<<4096, blk, 0, stream>>>(xacc, O, xacc, xn, g3, b3);

  // ---- MLP ----
  gemm_bt<1><<<dim3(32, 32), blk, 0, stream>>>(xn, W1t, h1, bf1, nullptr, 4096, 4096, 1024);
  gemm_bt<2><<<dim3(8, 32), blk, 0, stream>>>(h1, W2t, (void*)xacc, bf2, xacc, 4096, 1024, 4096);

  (void)in_sizes; (void)n_in; (void)out_size; (void)ws_size;
}

// Round 3
// 630.601 us; speedup vs baseline: 1.0073x; 1.0073x over previous
//
#include <hip/hip_runtime.h>

// ---------------------------------------------------------------------------
// Fused TransformerBlock: x += MSA(LN(x)) twice, then x += MLP(LN(x)).
// B=4 T=1024 C=1024 H=16 hd=64. All activations fp32 at residual level,
// bf16 at GEMM inputs (MFMA 16x16x32_bf16), softmax/LN/reductions fp32.
// ---------------------------------------------------------------------------

#define DEVI __device__ __forceinline__

typedef unsigned short u16;
typedef short bf16x8 __attribute__((ext_vector_type(8)));   // 8 bf16 = 4 VGPR
typedef float f32x4 __attribute__((ext_vector_type(4)));
typedef unsigned short u16x4 __attribute__((ext_vector_type(4)));

DEVI u16 f2bf(float f) {                 // RNE fp32 -> bf16
  union { float f; unsigned u; } v; v.f = f;
  unsigned r = v.u + 0x7FFFu + ((v.u >> 16) & 1u);
  return (u16)(r >> 16);
}

DEVI void gload16(const void* g, void* l) {   // async global->LDS, 16B/lane
  __builtin_amdgcn_global_load_lds((const __attribute__((address_space(1))) void*)g,
                                   (__attribute__((address_space(3))) void*)l,
                                   16, 0, 0);
}

// ---------------------------------------------------------------------------
// Weight packs (fp32 -> bf16, transposed to Bt[N][K] layout for the GEMM)
// ---------------------------------------------------------------------------

// W [16][1024][64] fp32  ->  out rows [h*64+d][1024] bf16
__global__ __launch_bounds__(256) void k_pack_headw(const float* __restrict__ W,
                                                    u16* __restrict__ out) {
  const int k0 = blockIdx.x * 64;
  const int h  = blockIdx.y;
  __shared__ float t[64][65];
  const int tid = threadIdx.x;
#pragma unroll
  for (int p = 0; p < 16; p++) {
    int e = p * 256 + tid, kk = e >> 6, d = e & 63;
    t[kk][d] = W[h * 65536 + (k0 + kk) * 64 + d];
  }
  __syncthreads();
#pragma unroll
  for (int p = 0; p < 16; p++) {
    int e = p * 256 + tid, d = e >> 6, kk = e & 63;
    out[(size_t)(h * 64 + d) * 1024 + k0 + kk] = f2bf(t[kk][d]);
  }
}

// in [R][C] fp32 -> out [C][R] bf16
__global__ __launch_bounds__(256) void k_transpose(const float* __restrict__ in,
                                                   u16* __restrict__ out,
                                                   int R, int C) {
  const int c0 = blockIdx.x * 64, r0 = blockIdx.y * 64;
  __shared__ float t[64][65];
  const int tid = threadIdx.x;
#pragma unroll
  for (int p = 0; p < 16; p++) {
    int e = p * 256 + tid, rr = e >> 6, cc = e & 63;
    t[rr][cc] = in[(size_t)(r0 + rr) * C + c0 + cc];
  }
  __syncthreads();
#pragma unroll
  for (int p = 0; p < 16; p++) {
    int e = p * 256 + tid, cc = e >> 6, rr = e & 63;
    out[(size_t)(c0 + cc) * R + r0 + rr] = f2bf(t[rr][cc]);
  }
}

// ---------------------------------------------------------------------------
// LayerNorm (optionally fused residual add): xv = xin (+ oin); writes fp32
// running residual (xsum) and bf16 normalized output (xn). One block per row.
// ---------------------------------------------------------------------------
__global__ __launch_bounds__(256) void k_ln(const float* __restrict__ xin,
                                            const float* __restrict__ oin,
                                            float* __restrict__ xsum,
                                            u16* __restrict__ xn,
                                            const float* __restrict__ g,
                                            const float* __restrict__ b) {
  const int row = blockIdx.x;
  const size_t base = (size_t)row * 1024;
  const int tid = threadIdx.x;
  float4 xv = ((const float4*)(xin + base))[tid];
  if (oin) {
    float4 ov = ((const float4*)(oin + base))[tid];
    xv.x += ov.x; xv.y += ov.y; xv.z += ov.z; xv.w += ov.w;
  }
  if (xsum) ((float4*)(xsum + base))[tid] = xv;
  float s = xv.x + xv.y + xv.z + xv.w;
  float q = xv.x * xv.x + xv.y * xv.y + xv.z * xv.z + xv.w * xv.w;
#pragma unroll
  for (int m = 1; m < 64; m <<= 1) { s += __shfl_xor(s, m); q += __shfl_xor(q, m); }
  __shared__ float red[8];
  const int wave = tid >> 6, lane = tid & 63;
  if (lane == 0) { red[wave] = s; red[4 + wave] = q; }
  __syncthreads();
  s = red[0] + red[1] + red[2] + red[3];
  q = red[4] + red[5] + red[6] + red[7];
  const float mean = s * (1.f / 1024.f);
  const float var  = q * (1.f / 1024.f) - mean * mean;
  const float rstd = rsqrtf(var + 1e-5f);
  float4 gv = ((const float4*)g)[tid];
  float4 bv = ((const float4*)b)[tid];
  u16x4 o;
  o[0] = f2bf((xv.x - mean) * rstd * gv.x + bv.x);
  o[1] = f2bf((xv.y - mean) * rstd * gv.y + bv.y);
  o[2] = f2bf((xv.z - mean) * rstd * gv.z + bv.z);
  o[3] = f2bf((xv.w - mean) * rstd * gv.w + bv.w);
  *(u16x4*)(xn + base + tid * 4) = o;
}

// ---------------------------------------------------------------------------
// GEMM C[M,N] = A[M,K] * Bt[N,K]^T, bf16 in, fp32 accum. m97 structure:
// 128x128 tile, BK=32, 4 waves (2x2) x 64x64, global_load_lds width-16.
// EPI 0: bf16 store. 1: +bias, relu, bf16. 2: +bias +resid, fp32 store.
// ---------------------------------------------------------------------------
template <int EPI>
__global__ __launch_bounds__(256) void gemm_bt(const u16* __restrict__ A,
                                               const u16* __restrict__ Bt,
                                               void* __restrict__ outp,
                                               const float* __restrict__ bias,
                                               const float* __restrict__ resid,
                                               int M, int N, int K) {
  __shared__ u16 As[128 * 32];
  __shared__ u16 Bs[128 * 32];
  const int tid = threadIdx.x;
  const int wave = tid >> 6, lane = tid & 63;
  const int lg = lane >> 4, l15 = lane & 15;
  const int wr = wave >> 1, wc = wave & 1;
  const int by = blockIdx.y, bx = blockIdx.x;

  const u16* Ab = A + (size_t)by * 128 * K;
  const u16* Bb = Bt + (size_t)bx * 128 * K;

  // staging: 512 chunks of 16B per 8KB tile; thread covers chunk tid and 256+tid
  const int r0 = tid >> 2, c0 = (tid & 3) * 8;
  const int r1 = (256 + tid) >> 2;
  char* lA0 = (char*)As + (wave * 64) * 16;          // wave-uniform LDS dst
  char* lA1 = (char*)As + (256 + wave * 64) * 16;
  char* lB0 = (char*)Bs + (wave * 64) * 16;
  char* lB1 = (char*)Bs + (256 + wave * 64) * 16;

  const f32x4 zero = {0.f, 0.f, 0.f, 0.f};
  f32x4 acc[4][4];
#pragma unroll
  for (int i = 0; i < 4; i++)
#pragma unroll
    for (int j = 0; j < 4; j++) acc[i][j] = zero;

  for (int kk = 0; kk < K; kk += 32) {
    gload16(Ab + (size_t)r0 * K + kk + c0, lA0);
    gload16(Ab + (size_t)r1 * K + kk + c0, lA1);
    gload16(Bb + (size_t)r0 * K + kk + c0, lB0);
    gload16(Bb + (size_t)r1 * K + kk + c0, lB1);
    __syncthreads();   // vmcnt(0) drain + barrier: tiles resident
    bf16x8 af[4], bfv[4];
#pragma unroll
    for (int i = 0; i < 4; i++)
      af[i] = *(const bf16x8*)&As[(wr * 64 + i * 16 + l15) * 32 + lg * 8];
#pragma unroll
    for (int j = 0; j < 4; j++)
      bfv[j] = *(const bf16x8*)&Bs[(wc * 64 + j * 16 + l15) * 32 + lg * 8];
#pragma unroll
    for (int i = 0; i < 4; i++)
#pragma unroll
      for (int j = 0; j < 4; j++)
        acc[i][j] = __builtin_amdgcn_mfma_f32_16x16x32_bf16(af[i], bfv[j], acc[i][j], 0, 0, 0);
    __syncthreads();   // all waves done reading before next stage overwrites
  }

  // C/D layout: col = lane&15, row = (lane>>4)*4 + reg  [m89/m91 verified]
  const int rbase = by * 128 + wr * 64 + lg * 4;
  const int cbase = bx * 128 + wc * 64 + l15;
  if constexpr (EPI == 0) {
    u16* out = (u16*)outp;
#pragma unroll
    for (int i = 0; i < 4; i++)
#pragma unroll
      for (int j = 0; j < 4; j++)
#pragma unroll
        for (int r = 0; r < 4; r++)
          out[(size_t)(rbase + i * 16 + r) * N + cbase + j * 16] = f2bf(acc[i][j][r]);
  } else if constexpr (EPI == 1) {
    u16* out = (u16*)outp;
#pragma unroll
    for (int j = 0; j < 4; j++) {
      const float bv = bias[cbase + j * 16];
#pragma unroll
      for (int i = 0; i < 4; i++)
#pragma unroll
        for (int r = 0; r < 4; r++)
          out[(size_t)(rbase + i * 16 + r) * N + cbase + j * 16] =
              f2bf(fmaxf(acc[i][j][r] + bv, 0.f));
    }
  } else {
    float* out = (float*)outp;
#pragma unroll
    for (int j = 0; j < 4; j++) {
      const float bv = bias[cbase + j * 16];
#pragma unroll
      for (int i = 0; i < 4; i++)
#pragma unroll
        for (int r = 0; r < 4; r++) {
          const size_t idx = (size_t)(rbase + i * 16 + r) * N + cbase + j * 16;
          out[idx] = acc[i][j][r] + bv + resid[idx];
        }
    }
  }
}

// ---------------------------------------------------------------------------
// V transpose: QKV[.,2048+h*64+d] -> Vt[b][h][d][t]  (bf16)
// ---------------------------------------------------------------------------
__global__ __launch_bounds__(256) void k_vt(const u16* __restrict__ QKV,
                                            u16* __restrict__ Vt) {
  const int bh = blockIdx.y, b = bh >> 4, h = bh & 15;
  const int t0 = blockIdx.x * 64;
  __shared__ u16 tile[64][66];
  const int tid = threadIdx.x;
#pragma unroll
  for (int p = 0; p < 16; p++) {
    int e = p * 256 + tid, tt = e >> 6, d = e & 63;
    tile[tt][d] = QKV[(size_t)(b * 1024 + t0 + tt) * 3072 + 2048 + h * 64 + d];
  }
  __syncthreads();
#pragma unroll
  for (int p = 0; p < 16; p++) {
    int e = p * 256 + tid, d = e >> 6, tt = e & 63;
    Vt[((size_t)bh * 64 + d) * 1024 + t0 + tt] = tile[tt][d];
  }
}

// ---------------------------------------------------------------------------
// Flash attention fwd, swapped-QK^T structure (P stays in registers).
// Block = (b,h) x 64 q-rows, 4 waves x 16 q-rows each. KVBLK=64.
// S^T = mfma(A=K, B=Q): lane holds S[kv][q=l15]. K rows are fed in a
// permuted order (tile t row r -> kv 8*(r>>2)+(r&3)+4*(t&1)+32*(t>>1)) so
// each lane ends holding exactly kv {8*lg..8*lg+7} (+32) — which IS the
// PV A-fragment layout. Softmax: 16 in-lane values + 2 shfl_xor (16,32).
// No LDS at all. Scale C^-0.5 = 1/32 folded into exp2.
// ---------------------------------------------------------------------------
__global__ __launch_bounds__(256) void k_attn(const u16* __restrict__ QKV,
                                              const u16* __restrict__ Vt,
                                              float* __restrict__ O) {
  const int Tn = 1024;
  const int bh = blockIdx.x, b = bh >> 4, h = bh & 15;
  const int q0 = blockIdx.y * 64;
  const int tid = threadIdx.x, wave = tid >> 6, lane = tid & 63;
  const int lg = lane >> 4, l15 = lane & 15;

  // Q fragment (B operand): Q[q=l15][d=8*lg+j], two d-blocks of 32
  const u16* Qb = QKV + (size_t)(b * Tn + q0 + wave * 16 + l15) * 3072 + h * 64 + lg * 8;
  const bf16x8 qf0 = *(const bf16x8*)Qb;
  const bf16x8 qf1 = *(const bf16x8*)(Qb + 32);

  const int kvperm = 8 * (l15 >> 2) + (l15 & 3);   // A-row -> kv within tile
  const u16* Kb = QKV + (size_t)(b * Tn) * 3072 + 1024 + h * 64 + lg * 8;
  const u16* Vb = Vt + (size_t)bh * 64 * Tn;

  const float cexp = 0.03125f * 1.44269504f;       // C^-0.5 * log2(e)

  float m = -1e30f, sden = 0.f;
  const f32x4 zero = {0.f, 0.f, 0.f, 0.f};
  f32x4 oa[4] = {zero, zero, zero, zero};

  for (int kv = 0; kv < Tn; kv += 64) {
    f32x4 s0 = zero, s1 = zero, s2 = zero, s3 = zero;
    {
      const u16* kp0 = Kb + (size_t)(kv + kvperm) * 3072;
      const u16* kp1 = Kb + (size_t)(kv + kvperm + 4) * 3072;
      const u16* kp2 = Kb + (size_t)(kv + kvperm + 32) * 3072;
      const u16* kp3 = Kb + (size_t)(kv + kvperm + 36) * 3072;
      s0 = __builtin_amdgcn_mfma_f32_16x16x32_bf16(*(const bf16x8*)kp0, qf0, s0, 0, 0, 0);
      s0 = __builtin_amdgcn_mfma_f32_16x16x32_bf16(*(const bf16x8*)(kp0 + 32), qf1, s0, 0, 0, 0);
      s1 = __builtin_amdgcn_mfma_f32_16x16x32_bf16(*(const bf16x8*)kp1, qf0, s1, 0, 0, 0);
      s1 = __builtin_amdgcn_mfma_f32_16x16x32_bf16(*(const bf16x8*)(kp1 + 32), qf1, s1, 0, 0, 0);
      s2 = __builtin_amdgcn_mfma_f32_16x16x32_bf16(*(const bf16x8*)kp2, qf0, s2, 0, 0, 0);
      s2 = __builtin_amdgcn_mfma_f32_16x16x32_bf16(*(const bf16x8*)(kp2 + 32), qf1, s2, 0, 0, 0);
      s3 = __builtin_amdgcn_mfma_f32_16x16x32_bf16(*(const bf16x8*)kp3, qf0, s3, 0, 0, 0);
      s3 = __builtin_amdgcn_mfma_f32_16x16x32_bf16(*(const bf16x8*)(kp3 + 32), qf1, s3, 0, 0, 0);
    }
    // lane now holds S[kv = 8*lg + {0..3,4..7,32..35,36..39}][q = l15]

    // --- online softmax over q = l15 (16 in-lane + 4-group cross-lane) ---
    f32x4 mv = s0;
#pragma unroll
    for (int r = 0; r < 4; r++) mv[r] = fmaxf(fmaxf(mv[r], s1[r]), fmaxf(s2[r], s3[r]));
    float mx = fmaxf(fmaxf(mv[0], mv[1]), fmaxf(mv[2], mv[3]));
    mx = fmaxf(mx, __shfl_xor(mx, 16));
    mx = fmaxf(mx, __shfl_xor(mx, 32));
    const float mn = fmaxf(m, mx);
    const float fr = exp2f((m - mn) * cexp);
    m = mn;
#pragma unroll
    for (int r = 0; r < 4; r++) {
      s0[r] = exp2f((s0[r] - mn) * cexp);
      s1[r] = exp2f((s1[r] - mn) * cexp);
      s2[r] = exp2f((s2[r] - mn) * cexp);
      s3[r] = exp2f((s3[r] - mn) * cexp);
    }
    f32x4 sv = (s0 + s1) + (s2 + s3);
    float ts = (sv[0] + sv[1]) + (sv[2] + sv[3]);
    ts += __shfl_xor(ts, 16);
    ts += __shfl_xor(ts, 32);
    sden = sden * fr + ts;

    // P fragments for PV (A operand): kv {8lg..8lg+7} and {32+8lg..32+8lg+7}
    bf16x8 pa0, pa1;
#pragma unroll
    for (int r = 0; r < 4; r++) {
      pa0[r]     = (short)f2bf(s0[r]);
      pa0[4 + r] = (short)f2bf(s1[r]);
      pa1[r]     = (short)f2bf(s2[r]);
      pa1[4 + r] = (short)f2bf(s3[r]);
    }

    // O rows held by this lane are q = 4*lg + r; fetch their rescale factors
    float frq[4];
#pragma unroll
    for (int r = 0; r < 4; r++) frq[r] = __shfl(fr, 20 * lg + r, 64);
#pragma unroll
    for (int dg = 0; dg < 4; dg++) {
      oa[dg][0] *= frq[0]; oa[dg][1] *= frq[1];
      oa[dg][2] *= frq[2]; oa[dg][3] *= frq[3];
      const u16* vp = Vb + (size_t)(dg * 16 + l15) * Tn + kv + lg * 8;
      oa[dg] = __builtin_amdgcn_mfma_f32_16x16x32_bf16(pa0, *(const bf16x8*)vp, oa[dg], 0, 0, 0);
      oa[dg] = __builtin_amdgcn_mfma_f32_16x16x32_bf16(pa1, *(const bf16x8*)(vp + 32), oa[dg], 0, 0, 0);
    }
  }

  float sdq[4];
#pragma unroll
  for (int r = 0; r < 4; r++) sdq[r] = 1.f / __shfl(sden, 20 * lg + r, 64);
  float* Ob = O + (size_t)(b * Tn + q0 + wave * 16) * 1024 + h * 64;
#pragma unroll
  for (int dg = 0; dg < 4; dg++)
#pragma unroll
    for (int r = 0; r < 4; r++)
      Ob[(size_t)(lg * 4 + r) * 1024 + dg * 16 + l15] = oa[dg][r] * sdq[r];
}

// ---------------------------------------------------------------------------
// Launch
// ---------------------------------------------------------------------------
extern "C" void kernel_launch(void* const* d_in, const int* in_sizes, int n_in,
                              void* d_out, int out_size, void* d_ws, size_t ws_size,
                              hipStream_t stream) {
  const float* x   = (const float*)d_in[0];
  const float* Wq1 = (const float*)d_in[1];
  const float* Wk1 = (const float*)d_in[2];
  const float* Wv1 = (const float*)d_in[3];
  const float* Wq2 = (const float*)d_in[4];
  const float* Wk2 = (const float*)d_in[5];
  const float* Wv2 = (const float*)d_in[6];
  const float* g1  = (const float*)d_in[7];
  const float* b1  = (const float*)d_in[8];
  const float* g2  = (const float*)d_in[9];
  const float* b2  = (const float*)d_in[10];
  const float* g3  = (const float*)d_in[11];
  const float* b3  = (const float*)d_in[12];
  const float* W1  = (const float*)d_in[13];
  const float* bf1 = (const float*)d_in[14];
  const float* W2  = (const float*)d_in[15];
  const float* bf2 = (const float*)d_in[16];

  char* ws = (char*)d_ws;
  // layout (bytes):
  u16* Wqkv1t = (u16*)(ws);                    //  6,291,456  [3072][1024]
  u16* Wqkv2t = (u16*)(ws + 6291456);          //  6,291,456
  u16* W1t    = (u16*)(ws + 12582912);         //  8,388,608  [4096][1024]
  u16* W2t    = (u16*)(ws + 20971520);         //  8,388,608  [1024][4096]
  u16* xn     = (u16*)(ws + 29360128);         //  8,388,608  [4096][1024]
  u16* QKV    = (u16*)(ws + 37748736);         // 25,165,824  [4096][3072]
  u16* Vt     = (u16*)(ws + 62914560);         //  8,388,608  [64][64][1024]
  float* O    = (float*)(ws + 71303168);       // 16,777,216  [4096][1024]
  u16* h1     = (u16*)(ws + 37748736);         // 33,554,432  aliases QKV+Vt (dead by MLP)
  float* xacc = (float*)d_out;                 // fp32 running residual lives in d_out
  // total ws = 88,080,384 bytes

  const dim3 blk(256);

  // weight packs
  k_pack_headw<<<dim3(16, 16), blk, 0, stream>>>(Wq1, Wqkv1t);
  k_pack_headw<<<dim3(16, 16), blk, 0, stream>>>(Wk1, Wqkv1t + 1024 * 1024);
  k_pack_headw<<<dim3(16, 16), blk, 0, stream>>>(Wv1, Wqkv1t + 2048 * 1024);
  k_pack_headw<<<dim3(16, 16), blk, 0, stream>>>(Wq2, Wqkv2t);
  k_pack_headw<<<dim3(16, 16), blk, 0, stream>>>(Wk2, Wqkv2t + 1024 * 1024);
  k_pack_headw<<<dim3(16, 16), blk, 0, stream>>>(Wv2, Wqkv2t + 2048 * 1024);
  k_transpose<<<dim3(64, 16), blk, 0, stream>>>(W1, W1t, 1024, 4096);
  k_transpose<<<dim3(16, 64), blk, 0, stream>>>(W2, W2t, 4096, 1024);

  // ---- layer 1 MSA ----
  k_ln<<<4096, blk, 0, stream>>>(x, nullptr, nullptr, xn, g1, b1);
  gemm_bt<0><<<dim3(24, 32), blk, 0, stream>>>(xn, Wqkv1t, QKV, nullptr, nullptr, 4096, 3072, 1024);
  k_vt<<<dim3(16, 64), blk, 0, stream>>>(QKV, Vt);
  k_attn<<<dim3(64, 16), blk, 0, stream>>>(QKV, Vt, O);
  // x2 = x + O; xn = LN(x2)
  k_ln<<<4096, blk, 0, stream>>>(x, O, xacc, xn, g2, b2);

  // ---- layer 2 MSA ----
  gemm_bt<0><<<dim3(24, 32), blk, 0, stream>>>(xn, Wqkv2t, QKV, nullptr, nullptr, 4096, 3072, 1024);
  k_vt<<<dim3(16, 64), blk, 0, stream>>>(QKV, Vt);
  k_attn<<<dim3(64, 16), blk, 0, stream>>>(QKV, Vt, O);
  // x3 = x2 + O (in place in d_out); xn = LN(x3)
  k_ln<<<4096, blk, 0, stream>>>(xacc, O, xacc, xn, g3, b3);

  // ---- MLP ----
  gemm_bt<1><<<dim3(32, 32), blk, 0, stream>>>(xn, W1t, h1, bf1, nullptr, 4096, 4096, 1024);
  gemm_bt<2><<<dim3(8, 32), blk, 0, stream>>>(h1, W2t, (void*)xacc, bf2, xacc, 4096, 1024, 4096);

  (void)in_sizes; (void)n_in; (void)out_size; (void)ws_size;
}